// Round 1
// baseline (1377.584 us; speedup 1.0000x reference)
//
#include <hip/hip_runtime.h>
#include <cstdint>
#include <cstddef>

#define BB 8
#define SS 4096
#define HH 1024
#define NHH 16
#define HDD 64
#define MM (BB*SS)   // 32768

typedef __attribute__((ext_vector_type(8))) short short8_t;
typedef __attribute__((ext_vector_type(4))) float f32x4;

__device__ __forceinline__ float bf2f(short u) {
  unsigned int x = ((unsigned int)(unsigned short)u) << 16;
  return __uint_as_float(x);
}
__device__ __forceinline__ short f2bf(float f) {
  unsigned int u = __float_as_uint(f);
  u += 0x7FFFu + ((u >> 16) & 1u);
  return (short)(u >> 16);
}

// ---------------- fp32 -> bf16 convert (vectorized) ----------------
__global__ void cvt_bf16(const float* __restrict__ in, short* __restrict__ out, int n4) {
  int i = blockIdx.x * blockDim.x + threadIdx.x;
  if (i >= n4) return;
  float4 v = ((const float4*)in)[i];
  short4 o;
  o.x = f2bf(v.x); o.y = f2bf(v.y); o.z = f2bf(v.z); o.w = f2bf(v.w);
  ((short4*)out)[i] = o;
}

// ---------------- bf16 GEMM: C = act(A[M,K] @ W[N,K]^T + bias[N]) ----------------
// 128x128 tile, BK=32, 256 threads (4 waves), each wave a 64x64 quadrant of 4x4
// mfma_f32_16x16x32_bf16 tiles. ACT=1 applies elu(x)+1.
template<int ACT>
__global__ __launch_bounds__(256, 2) void gemm_bt(
    const short* __restrict__ A, const short* __restrict__ W,
    const float* __restrict__ bias, short* __restrict__ C,
    int M, int N, int K)
{
  __shared__ __align__(16) short sA[128*32];
  __shared__ __align__(16) short sW[128*32];
  const int t    = threadIdx.x;
  const int lane = t & 63;
  const int wave = t >> 6;
  const int m0 = blockIdx.y * 128;
  const int n0 = blockIdx.x * 128;
  const int wr = (wave >> 1) * 64;   // wave row quadrant
  const int wc = (wave & 1) * 64;    // wave col quadrant
  const int srow = t >> 2;           // staging row 0..63
  const int scol = (t & 3) * 8;      // staging col (elements)
  const int fr = lane & 15;          // fragment row
  const int fk = (lane >> 4) * 8;    // fragment k offset

  f32x4 acc[4][4] = {};

  const short* Abase = A + (size_t)(m0 + srow) * K + scol;
  const short* Wbase = W + (size_t)(n0 + srow) * K + scol;

  for (int k0 = 0; k0 < K; k0 += 32) {
    short8_t a0 = *(const short8_t*)(Abase + k0);
    short8_t a1 = *(const short8_t*)(Abase + (size_t)64 * K + k0);
    short8_t w0 = *(const short8_t*)(Wbase + k0);
    short8_t w1 = *(const short8_t*)(Wbase + (size_t)64 * K + k0);
    __syncthreads();
    *(short8_t*)(sA + srow * 32 + scol)        = a0;
    *(short8_t*)(sA + (64 + srow) * 32 + scol) = a1;
    *(short8_t*)(sW + srow * 32 + scol)        = w0;
    *(short8_t*)(sW + (64 + srow) * 32 + scol) = w1;
    __syncthreads();

    short8_t af[4], wf[4];
    #pragma unroll
    for (int i = 0; i < 4; i++)
      af[i] = *(const short8_t*)(sA + (wr + i * 16 + fr) * 32 + fk);
    #pragma unroll
    for (int j = 0; j < 4; j++)
      wf[j] = *(const short8_t*)(sW + (wc + j * 16 + fr) * 32 + fk);
    #pragma unroll
    for (int i = 0; i < 4; i++) {
      #pragma unroll
      for (int j = 0; j < 4; j++) {
        acc[i][j] = __builtin_amdgcn_mfma_f32_16x16x32_bf16(af[i], wf[j], acc[i][j], 0, 0, 0);
      }
    }
  }

  // epilogue: D[row=(lane>>4)*4+r][col=lane&15] per 16x16 subtile
  const int cr = (lane >> 4) * 4;
  const int cc = lane & 15;
  #pragma unroll
  for (int j = 0; j < 4; j++) {
    const int col = n0 + wc + j * 16 + cc;
    const float bv = bias[col];
    #pragma unroll
    for (int i = 0; i < 4; i++) {
      #pragma unroll
      for (int r = 0; r < 4; r++) {
        const int row = m0 + wr + i * 16 + cr + r;
        float v = acc[i][j][r] + bv;
        if (ACT) v = (v > 0.f) ? (v + 1.f) : __expf(v);
        C[(size_t)row * N + col] = f2bf(v);
      }
    }
  }
}

// ---------------- kv[b,h,m,d] = sum_s K[b,s,h,d]*V[b,s,h,m]; ksum[b,h,d] ----------------
// one block per (b,h); 256 threads: thread = (m = t&63, dgroup = t>>6 covering 16 d's)
__global__ __launch_bounds__(256) void kv_ksum_kernel(
    const short* __restrict__ K_, const short* __restrict__ V_,
    float* __restrict__ kv, float* __restrict__ ksum)
{
  __shared__ __align__(16) float sK[32 * 64];
  __shared__ __align__(16) float sV[32 * 64];
  const int h = blockIdx.x, b = blockIdx.y;
  const int t = threadIdx.x;
  const int m = t & 63;
  const int dg = (t >> 6) * 16;
  const int lrow = t >> 3;        // 0..31
  const int lcol = (t & 7) * 8;   // 0..56
  float acc[16] = {};
  float ks = 0.f;
  const size_t base = ((size_t)b * SS) * HH + (size_t)h * HDD;
  const short* Kp = K_ + base + (size_t)lrow * HH + lcol;
  const short* Vp = V_ + base + (size_t)lrow * HH + lcol;

  for (int sc = 0; sc < SS; sc += 32) {
    short8_t k8 = *(const short8_t*)(Kp + (size_t)sc * HH);
    short8_t v8 = *(const short8_t*)(Vp + (size_t)sc * HH);
    __syncthreads();
    #pragma unroll
    for (int j = 0; j < 8; j++) {
      sK[lrow * 64 + lcol + j] = bf2f(k8[j]);
      sV[lrow * 64 + lcol + j] = bf2f(v8[j]);
    }
    __syncthreads();
    if (t < 64) {
      #pragma unroll
      for (int ss = 0; ss < 32; ss++) ks += sK[ss * 64 + t];
    }
    #pragma unroll 4
    for (int ss = 0; ss < 32; ss++) {
      const float vm = sV[ss * 64 + m];
      const float* kr = sK + ss * 64 + dg;
      #pragma unroll
      for (int j = 0; j < 16; j++) acc[j] += kr[j] * vm;
    }
  }

  float* kvp = kv + (((size_t)(b * NHH + h) * 64) + m) * 64 + dg;
  #pragma unroll
  for (int j = 0; j < 16; j += 4) {
    f32x4 o;
    o[0] = acc[j]; o[1] = acc[j+1]; o[2] = acc[j+2]; o[3] = acc[j+3];
    *(f32x4*)(kvp + j) = o;
  }
  if (t < 64) ksum[(b * NHH + h) * 64 + t] = ks + 1e-6f;
}

// ---------------- ctx[b,s,h,m] = z * sum_d q[d]*kv[m,d], z = 1/(q . ksum) ----------------
// block per (b,h,256 tokens); kv tile in LDS (broadcast reads); one thread per token.
__global__ __launch_bounds__(256) void ctx_kernel(
    const short* __restrict__ Q, const float* __restrict__ kv,
    const float* __restrict__ ksum, short* __restrict__ ctx)
{
  __shared__ __align__(16) float skv[64 * 64];
  __shared__ __align__(16) float sks[64];
  const int b = blockIdx.z, h = blockIdx.y;
  const int t = threadIdx.x;
  const int s = blockIdx.x * 256 + t;
  const float* kvp = kv + (size_t)(b * NHH + h) * 4096;
  #pragma unroll
  for (int i = 0; i < 4; i++)
    ((f32x4*)skv)[t + i * 256] = ((const f32x4*)kvp)[t + i * 256];
  if (t < 64) sks[t] = ksum[(b * NHH + h) * 64 + t];
  __syncthreads();

  const short* qp = Q + (size_t)(b * SS + s) * HH + h * HDD;
  float q[64];
  #pragma unroll
  for (int i = 0; i < 8; i++) {
    short8_t q8 = *(const short8_t*)(qp + i * 8);
    #pragma unroll
    for (int j = 0; j < 8; j++) q[i * 8 + j] = bf2f(q8[j]);
  }
  float zden = 0.f;
  #pragma unroll
  for (int d = 0; d < 64; d++) zden += q[d] * sks[d];
  const float z = 1.f / zden;

  short* cp = ctx + (size_t)(b * SS + s) * HH + h * HDD;
  for (int mo = 0; mo < 8; mo++) {
    short8_t ob;
    #pragma unroll
    for (int mi = 0; mi < 8; mi++) {
      const int mm = mo * 8 + mi;
      const float* kr = skv + mm * 64;
      float a = 0.f;
      #pragma unroll
      for (int d = 0; d < 64; d++) a += q[d] * kr[d];
      ob[mi] = f2bf(a * z);
    }
    *(short8_t*)(cp + mo * 8) = ob;
  }
}

// ---------------- LayerNorm(P + x) * gamma + beta ----------------
__global__ __launch_bounds__(256) void ln_kernel(
    const short* __restrict__ P, const float* __restrict__ x,
    const float* __restrict__ gamma, const float* __restrict__ beta,
    float* __restrict__ out)
{
  const int row = blockIdx.x;
  const int t = threadIdx.x;
  const short* pr = P + (size_t)row * HH;
  const float* xr = x + (size_t)row * HH;
  short4 p4 = ((const short4*)pr)[t];
  float4 x4 = ((const float4*)xr)[t];
  float h0 = bf2f(p4.x) + x4.x;
  float h1 = bf2f(p4.y) + x4.y;
  float h2 = bf2f(p4.z) + x4.z;
  float h3 = bf2f(p4.w) + x4.w;
  float s1 = h0 + h1 + h2 + h3;
  float s2 = h0*h0 + h1*h1 + h2*h2 + h3*h3;
  #pragma unroll
  for (int o = 32; o > 0; o >>= 1) {
    s1 += __shfl_xor(s1, o);
    s2 += __shfl_xor(s2, o);
  }
  __shared__ float red[8];
  const int wv = t >> 6, ln = t & 63;
  if (ln == 0) { red[wv] = s1; red[4 + wv] = s2; }
  __syncthreads();
  const float S1 = red[0] + red[1] + red[2] + red[3];
  const float S2 = red[4] + red[5] + red[6] + red[7];
  const float mu  = S1 * (1.f / HH);
  const float var = S2 * (1.f / HH) - mu * mu;
  const float inv = rsqrtf(var + 1e-12f);
  float4 g4 = ((const float4*)gamma)[t];
  float4 b4 = ((const float4*)beta)[t];
  float4 o4;
  o4.x = (h0 - mu) * inv * g4.x + b4.x;
  o4.y = (h1 - mu) * inv * g4.y + b4.y;
  o4.z = (h2 - mu) * inv * g4.z + b4.z;
  o4.w = (h3 - mu) * inv * g4.w + b4.w;
  ((float4*)(out + (size_t)row * HH))[t] = o4;
}

extern "C" void kernel_launch(void* const* d_in, const int* in_sizes, int n_in,
                              void* d_out, int out_size, void* d_ws, size_t ws_size,
                              hipStream_t stream)
{
  const float* x     = (const float*)d_in[0];
  // d_in[1] = attention_mask: unused by the reference computation
  const float* Wq    = (const float*)d_in[2];
  const float* bq    = (const float*)d_in[3];
  const float* Wk    = (const float*)d_in[4];
  const float* bk    = (const float*)d_in[5];
  const float* Wv    = (const float*)d_in[6];
  const float* bv    = (const float*)d_in[7];
  const float* Wd    = (const float*)d_in[8];
  const float* bd    = (const float*)d_in[9];
  const float* gamma = (const float*)d_in[10];
  const float* beta  = (const float*)d_in[11];
  float* out = (float*)d_out;

  char* ws = (char*)d_ws;
  const size_t MB64 = 67108864;  // 32768*1024*2 bytes
  short* xb  = (short*)(ws + 0 * MB64);
  short* Qb  = (short*)(ws + 1 * MB64);
  short* Kb  = (short*)(ws + 2 * MB64);
  short* Vb  = (short*)(ws + 3 * MB64);
  short* Cb  = (short*)(ws + 4 * MB64);
  short* Wqb = (short*)(ws + 5 * MB64 + 0 * 2097152);
  short* Wkb = (short*)(ws + 5 * MB64 + 1 * 2097152);
  short* Wvb = (short*)(ws + 5 * MB64 + 2 * 2097152);
  short* Wdb = (short*)(ws + 5 * MB64 + 3 * 2097152);
  float* kvb = (float*)(ws + 5 * MB64 + 4 * 2097152);
  float* ksb = (float*)(ws + 5 * MB64 + 5 * 2097152);
  short* Pb  = Qb;  // Q is dead after ctx_kernel; reuse for projection output

  // convert inputs to bf16
  cvt_bf16<<<(MM * HH / 4) / 256, 256, 0, stream>>>(x,  xb,  MM * HH / 4);
  cvt_bf16<<<(HH * HH / 4) / 256, 256, 0, stream>>>(Wq, Wqb, HH * HH / 4);
  cvt_bf16<<<(HH * HH / 4) / 256, 256, 0, stream>>>(Wk, Wkb, HH * HH / 4);
  cvt_bf16<<<(HH * HH / 4) / 256, 256, 0, stream>>>(Wv, Wvb, HH * HH / 4);
  cvt_bf16<<<(HH * HH / 4) / 256, 256, 0, stream>>>(Wd, Wdb, HH * HH / 4);

  dim3 gg(HH / 128, MM / 128);
  gemm_bt<1><<<gg, 256, 0, stream>>>(xb, Wqb, bq, Qb, MM, HH, HH);
  gemm_bt<1><<<gg, 256, 0, stream>>>(xb, Wkb, bk, Kb, MM, HH, HH);
  gemm_bt<0><<<gg, 256, 0, stream>>>(xb, Wvb, bv, Vb, MM, HH, HH);

  kv_ksum_kernel<<<dim3(NHH, BB), 256, 0, stream>>>(Kb, Vb, kvb, ksb);
  ctx_kernel<<<dim3(SS / 256, NHH, BB), 256, 0, stream>>>(Qb, kvb, ksb, Cb);

  gemm_bt<0><<<gg, 256, 0, stream>>>(Cb, Wdb, bd, Pb, MM, HH, HH);
  ln_kernel<<<MM, 256, 0, stream>>>(Pb, x, gamma, beta, out);
}

// Round 2
// 910.420 us; speedup vs baseline: 1.5131x; 1.5131x over previous
//
#include <hip/hip_runtime.h>
#include <cstdint>
#include <cstddef>

#define BB 8
#define SS 4096
#define HH 1024
#define NHH 16
#define HDD 64
#define MM (BB*SS)   // 32768
#define KVSPLIT 16

typedef __attribute__((ext_vector_type(8))) short short8_t;
typedef __attribute__((ext_vector_type(4))) float f32x4;

__device__ __forceinline__ float bf2f(short u) {
  unsigned int x = ((unsigned int)(unsigned short)u) << 16;
  return __uint_as_float(x);
}
__device__ __forceinline__ short f2bf(float f) {
  unsigned int u = __float_as_uint(f);
  u += 0x7FFFu + ((u >> 16) & 1u);
  return (short)(u >> 16);
}

__device__ __forceinline__ void gload_lds16(const void* g, void* l) {
  __builtin_amdgcn_global_load_lds(
      (const __attribute__((address_space(1))) void*)g,
      (__attribute__((address_space(3))) void*)l, 16, 0, 0);
}

// ---------------- fp32 -> bf16 convert (vectorized) ----------------
__global__ void cvt_bf16(const float* __restrict__ in, short* __restrict__ out, int n4) {
  int i = blockIdx.x * blockDim.x + threadIdx.x;
  if (i >= n4) return;
  float4 v = ((const float4*)in)[i];
  short4 o;
  o.x = f2bf(v.x); o.y = f2bf(v.y); o.z = f2bf(v.z); o.w = f2bf(v.w);
  ((short4*)out)[i] = o;
}

// ---------------- bf16 GEMM: C = act(A[M,K] @ W[N,K]^T + bias[N]) ----------------
// 128x128 tile, BK=32, 256 threads (4 waves), each wave a 64x64 quadrant of 4x4
// mfma_f32_16x16x32_bf16 tiles. Staging via global_load_lds width=16 (m97
// structure): thread t's LDS dest byte = t*16 == wave_base + lane*16. ACT=1
// applies elu(x)+1.
template<int ACT>
__global__ __launch_bounds__(256, 2) void gemm_bt(
    const short* __restrict__ A, const short* __restrict__ W,
    const float* __restrict__ bias, short* __restrict__ C,
    int M, int N, int K)
{
  __shared__ __align__(16) short sA[128*32];
  __shared__ __align__(16) short sW[128*32];
  const int t    = threadIdx.x;
  const int lane = t & 63;
  const int wave = t >> 6;
  const int m0 = blockIdx.y * 128;
  const int n0 = blockIdx.x * 128;
  const int wr = (wave >> 1) * 64;   // wave row quadrant
  const int wc = (wave & 1) * 64;    // wave col quadrant
  const int srow = t >> 2;           // staging row 0..63
  const int scol = (t & 3) * 8;      // staging col (elements)
  const int fr = lane & 15;          // fragment row
  const int fk = (lane >> 4) * 8;    // fragment k offset

  f32x4 acc[4][4] = {};

  const short* Abase = A + (size_t)(m0 + srow) * K + scol;
  const short* Wbase = W + (size_t)(n0 + srow) * K + scol;
  char* lA0 = (char*)sA + t * 16;
  char* lA1 = (char*)sA + 4096 + t * 16;
  char* lW0 = (char*)sW + t * 16;
  char* lW1 = (char*)sW + 4096 + t * 16;

  for (int k0 = 0; k0 < K; k0 += 32) {
    __syncthreads();   // previous iteration's LDS reads complete
    gload_lds16(Abase + k0,                  lA0);
    gload_lds16(Abase + (size_t)64 * K + k0, lA1);
    gload_lds16(Wbase + k0,                  lW0);
    gload_lds16(Wbase + (size_t)64 * K + k0, lW1);
    __syncthreads();   // drains vmcnt(0): staged data visible

    short8_t af[4], wf[4];
    #pragma unroll
    for (int i = 0; i < 4; i++)
      af[i] = *(const short8_t*)(sA + (wr + i * 16 + fr) * 32 + fk);
    #pragma unroll
    for (int j = 0; j < 4; j++)
      wf[j] = *(const short8_t*)(sW + (wc + j * 16 + fr) * 32 + fk);
    #pragma unroll
    for (int i = 0; i < 4; i++) {
      #pragma unroll
      for (int j = 0; j < 4; j++) {
        acc[i][j] = __builtin_amdgcn_mfma_f32_16x16x32_bf16(af[i], wf[j], acc[i][j], 0, 0, 0);
      }
    }
  }

  // epilogue: D[row=(lane>>4)*4+r][col=lane&15] per 16x16 subtile
  const int cr = (lane >> 4) * 4;
  const int cc = lane & 15;
  #pragma unroll
  for (int j = 0; j < 4; j++) {
    const int col = n0 + wc + j * 16 + cc;
    const float bv = bias[col];
    #pragma unroll
    for (int i = 0; i < 4; i++) {
      #pragma unroll
      for (int r = 0; r < 4; r++) {
        const int row = m0 + wr + i * 16 + cr + r;
        float v = acc[i][j][r] + bv;
        if (ACT) v = (v > 0.f) ? (v + 1.f) : __expf(v);
        C[(size_t)row * N + col] = f2bf(v);
      }
    }
  }
}

// ---------------- kv partials over S-splits ----------------
// kvpart[bh, sp, m, d] = sum_{s in split sp} K[b,s,h,d]*V[b,s,h,m]
// kspart[bh, sp, d]    = sum_{s in split sp} K[b,s,h,d]
// grid (NHH, BB, KVSPLIT), 256 threads: thread = (m = t&63, dgroup = (t>>6)*16)
__global__ __launch_bounds__(256) void kv_part_kernel(
    const short* __restrict__ K_, const short* __restrict__ V_,
    float* __restrict__ kvpart, float* __restrict__ kspart)
{
  __shared__ __align__(16) float sK[32 * 64];
  __shared__ __align__(16) float sV[32 * 64];
  const int h = blockIdx.x, b = blockIdx.y, sp = blockIdx.z;
  const int t = threadIdx.x;
  const int m = t & 63;
  const int dg = (t >> 6) * 16;
  const int lrow = t >> 3;        // 0..31
  const int lcol = (t & 7) * 8;   // 0..56
  const int SC = SS / KVSPLIT;    // 256 rows per split
  float acc[16] = {};
  float ks = 0.f;
  const size_t base = ((size_t)b * SS + (size_t)sp * SC) * HH + (size_t)h * HDD;
  const short* Kp = K_ + base + (size_t)lrow * HH + lcol;
  const short* Vp = V_ + base + (size_t)lrow * HH + lcol;

  for (int sc = 0; sc < SC; sc += 32) {
    short8_t k8 = *(const short8_t*)(Kp + (size_t)sc * HH);
    short8_t v8 = *(const short8_t*)(Vp + (size_t)sc * HH);
    __syncthreads();
    #pragma unroll
    for (int j = 0; j < 8; j++) {
      sK[lrow * 64 + lcol + j] = bf2f(k8[j]);
      sV[lrow * 64 + lcol + j] = bf2f(v8[j]);
    }
    __syncthreads();
    if (t < 64) {
      #pragma unroll
      for (int ss = 0; ss < 32; ss++) ks += sK[ss * 64 + t];
    }
    #pragma unroll 4
    for (int ss = 0; ss < 32; ss++) {
      const float vm = sV[ss * 64 + m];
      const float* kr = sK + ss * 64 + dg;
      #pragma unroll
      for (int j = 0; j < 16; j++) acc[j] += kr[j] * vm;
    }
  }

  const int bh = b * NHH + h;
  float* kvp = kvpart + (size_t)(bh * KVSPLIT + sp) * 4096 + m * 64 + dg;
  #pragma unroll
  for (int j = 0; j < 16; j += 4) {
    f32x4 o;
    o[0] = acc[j]; o[1] = acc[j+1]; o[2] = acc[j+2]; o[3] = acc[j+3];
    *(f32x4*)(kvp + j) = o;
  }
  if (t < 64) kspart[(bh * KVSPLIT + sp) * 64 + t] = ks;
}

// ---------------- reduce partials: kv[bh,4096], ksum[bh,64] ----------------
__global__ __launch_bounds__(256) void kv_reduce_kernel(
    const float* __restrict__ kvpart, const float* __restrict__ kspart,
    float* __restrict__ kv, float* __restrict__ ksum)
{
  const int bh = blockIdx.x;
  const int t = threadIdx.x;
  const float* src = kvpart + (size_t)bh * KVSPLIT * 4096;
  #pragma unroll
  for (int i = 0; i < 4; i++) {
    const int idx = t + i * 256;  // f32x4 index within 1024
    f32x4 s = {};
    #pragma unroll 4
    for (int p = 0; p < KVSPLIT; p++)
      s += ((const f32x4*)(src + (size_t)p * 4096))[idx];
    ((f32x4*)(kv + (size_t)bh * 4096))[idx] = s;
  }
  if (t < 64) {
    float s = 0.f;
    #pragma unroll
    for (int p = 0; p < KVSPLIT; p++) s += kspart[(bh * KVSPLIT + p) * 64 + t];
    ksum[bh * 64 + t] = s + 1e-6f;
  }
}

// ---------------- ctx[b,s,h,m] = z * sum_d q[d]*kv[m,d], z = 1/(q . ksum) ----------------
__global__ __launch_bounds__(256) void ctx_kernel(
    const short* __restrict__ Q, const float* __restrict__ kv,
    const float* __restrict__ ksum, short* __restrict__ ctx)
{
  __shared__ __align__(16) float skv[64 * 64];
  __shared__ __align__(16) float sks[64];
  const int b = blockIdx.z, h = blockIdx.y;
  const int t = threadIdx.x;
  const int s = blockIdx.x * 256 + t;
  const float* kvp = kv + (size_t)(b * NHH + h) * 4096;
  #pragma unroll
  for (int i = 0; i < 4; i++)
    ((f32x4*)skv)[t + i * 256] = ((const f32x4*)kvp)[t + i * 256];
  if (t < 64) sks[t] = ksum[(b * NHH + h) * 64 + t];
  __syncthreads();

  const short* qp = Q + (size_t)(b * SS + s) * HH + h * HDD;
  float q[64];
  #pragma unroll
  for (int i = 0; i < 8; i++) {
    short8_t q8 = *(const short8_t*)(qp + i * 8);
    #pragma unroll
    for (int j = 0; j < 8; j++) q[i * 8 + j] = bf2f(q8[j]);
  }
  float zden = 0.f;
  #pragma unroll
  for (int d = 0; d < 64; d++) zden += q[d] * sks[d];
  const float z = 1.f / zden;

  short* cp = ctx + (size_t)(b * SS + s) * HH + h * HDD;
  for (int mo = 0; mo < 8; mo++) {
    short8_t ob;
    #pragma unroll
    for (int mi = 0; mi < 8; mi++) {
      const int mm = mo * 8 + mi;
      const float* kr = skv + mm * 64;
      float a = 0.f;
      #pragma unroll
      for (int d4 = 0; d4 < 16; d4++) {
        f32x4 kk = *(const f32x4*)(kr + d4 * 4);
        a += q[d4*4+0] * kk[0] + q[d4*4+1] * kk[1] + q[d4*4+2] * kk[2] + q[d4*4+3] * kk[3];
      }
      ob[mi] = f2bf(a * z);
    }
    *(short8_t*)(cp + mo * 8) = ob;
  }
}

// ---------------- LayerNorm(P + x) * gamma + beta ----------------
__global__ __launch_bounds__(256) void ln_kernel(
    const short* __restrict__ P, const float* __restrict__ x,
    const float* __restrict__ gamma, const float* __restrict__ beta,
    float* __restrict__ out)
{
  const int row = blockIdx.x;
  const int t = threadIdx.x;
  const short* pr = P + (size_t)row * HH;
  const float* xr = x + (size_t)row * HH;
  short4 p4 = ((const short4*)pr)[t];
  float4 x4 = ((const float4*)xr)[t];
  float h0 = bf2f(p4.x) + x4.x;
  float h1 = bf2f(p4.y) + x4.y;
  float h2 = bf2f(p4.z) + x4.z;
  float h3 = bf2f(p4.w) + x4.w;
  float s1 = h0 + h1 + h2 + h3;
  float s2 = h0*h0 + h1*h1 + h2*h2 + h3*h3;
  #pragma unroll
  for (int o = 32; o > 0; o >>= 1) {
    s1 += __shfl_xor(s1, o);
    s2 += __shfl_xor(s2, o);
  }
  __shared__ float red[8];
  const int wv = t >> 6, ln = t & 63;
  if (ln == 0) { red[wv] = s1; red[4 + wv] = s2; }
  __syncthreads();
  const float S1 = red[0] + red[1] + red[2] + red[3];
  const float S2 = red[4] + red[5] + red[6] + red[7];
  const float mu  = S1 * (1.f / HH);
  const float var = S2 * (1.f / HH) - mu * mu;
  const float inv = rsqrtf(var + 1e-12f);
  float4 g4 = ((const float4*)gamma)[t];
  float4 b4 = ((const float4*)beta)[t];
  float4 o4;
  o4.x = (h0 - mu) * inv * g4.x + b4.x;
  o4.y = (h1 - mu) * inv * g4.y + b4.y;
  o4.z = (h2 - mu) * inv * g4.z + b4.z;
  o4.w = (h3 - mu) * inv * g4.w + b4.w;
  ((float4*)(out + (size_t)row * HH))[t] = o4;
}

extern "C" void kernel_launch(void* const* d_in, const int* in_sizes, int n_in,
                              void* d_out, int out_size, void* d_ws, size_t ws_size,
                              hipStream_t stream)
{
  const float* x     = (const float*)d_in[0];
  // d_in[1] = attention_mask: unused (all zeros; reference ignores it)
  const float* Wq    = (const float*)d_in[2];
  const float* bq    = (const float*)d_in[3];
  const float* Wk    = (const float*)d_in[4];
  const float* bk    = (const float*)d_in[5];
  const float* Wv    = (const float*)d_in[6];
  const float* bv    = (const float*)d_in[7];
  const float* Wd    = (const float*)d_in[8];
  const float* bd    = (const float*)d_in[9];
  const float* gamma = (const float*)d_in[10];
  const float* beta  = (const float*)d_in[11];
  float* out = (float*)d_out;

  char* ws = (char*)d_ws;
  const size_t MB64 = 67108864;  // 32768*1024*2 bytes
  short* xb  = (short*)(ws + 0 * MB64);
  short* Qb  = (short*)(ws + 1 * MB64);
  short* Kb  = (short*)(ws + 2 * MB64);
  short* Vb  = (short*)(ws + 3 * MB64);
  short* Cb  = (short*)(ws + 4 * MB64);
  short* Wqb = (short*)(ws + 5 * MB64 + 0 * 2097152);
  short* Wkb = (short*)(ws + 5 * MB64 + 1 * 2097152);
  short* Wvb = (short*)(ws + 5 * MB64 + 2 * 2097152);
  short* Wdb = (short*)(ws + 5 * MB64 + 3 * 2097152);
  float* kvb = (float*)(ws + 5 * MB64 + 4 * 2097152);
  float* ksb = (float*)(ws + 5 * MB64 + 5 * 2097152);
  // kv partials overlay the Cb region (Cb not live until ctx_kernel):
  // 128*16*4096*4 = 33.5 MB + 0.5 MB kspart <= 64 MB region
  float* kvpart = (float*)(ws + 4 * MB64);
  float* kspart = kvpart + (size_t)128 * KVSPLIT * 4096;
  short* Pb  = Qb;  // Q is dead after ctx_kernel; reuse for projection output

  // convert inputs to bf16
  cvt_bf16<<<(MM * HH / 4) / 256, 256, 0, stream>>>(x,  xb,  MM * HH / 4);
  cvt_bf16<<<(HH * HH / 4) / 256, 256, 0, stream>>>(Wq, Wqb, HH * HH / 4);
  cvt_bf16<<<(HH * HH / 4) / 256, 256, 0, stream>>>(Wk, Wkb, HH * HH / 4);
  cvt_bf16<<<(HH * HH / 4) / 256, 256, 0, stream>>>(Wv, Wvb, HH * HH / 4);
  cvt_bf16<<<(HH * HH / 4) / 256, 256, 0, stream>>>(Wd, Wdb, HH * HH / 4);

  dim3 gg(HH / 128, MM / 128);
  gemm_bt<1><<<gg, 256, 0, stream>>>(xb, Wqb, bq, Qb, MM, HH, HH);
  gemm_bt<1><<<gg, 256, 0, stream>>>(xb, Wkb, bk, Kb, MM, HH, HH);
  gemm_bt<0><<<gg, 256, 0, stream>>>(xb, Wvb, bv, Vb, MM, HH, HH);

  kv_part_kernel<<<dim3(NHH, BB, KVSPLIT), 256, 0, stream>>>(Kb, Vb, kvpart, kspart);
  kv_reduce_kernel<<<BB * NHH, 256, 0, stream>>>(kvpart, kspart, kvb, ksb);
  ctx_kernel<<<dim3(SS / 256, NHH, BB), 256, 0, stream>>>(Qb, kvb, ksb, Cb);

  gemm_bt<0><<<gg, 256, 0, stream>>>(Cb, Wdb, bd, Pb, MM, HH, HH);
  ln_kernel<<<MM, 256, 0, stream>>>(Pb, x, gamma, beta, out);
}

// Round 3
// 780.070 us; speedup vs baseline: 1.7660x; 1.1671x over previous
//
#include <hip/hip_runtime.h>
#include <cstdint>
#include <cstddef>

#define BB 8
#define SS 4096
#define HH 1024
#define NHH 16
#define HDD 64
#define MM (BB*SS)   // 32768
#define KVSPLIT 16

typedef __attribute__((ext_vector_type(8))) short short8_t;
typedef __attribute__((ext_vector_type(4))) float f32x4;

__device__ __forceinline__ float bf2f(short u) {
  unsigned int x = ((unsigned int)(unsigned short)u) << 16;
  return __uint_as_float(x);
}
__device__ __forceinline__ short f2bf(float f) {
  unsigned int u = __float_as_uint(f);
  u += 0x7FFFu + ((u >> 16) & 1u);
  return (short)(u >> 16);
}

__device__ __forceinline__ void gload_lds16(const void* g, void* l) {
  __builtin_amdgcn_global_load_lds(
      (const __attribute__((address_space(1))) void*)g,
      (__attribute__((address_space(3))) void*)l, 16, 0, 0);
}

// ---------------- fp32 -> bf16 convert (vectorized) ----------------
__global__ void cvt_bf16(const float* __restrict__ in, short* __restrict__ out, int n4) {
  int i = blockIdx.x * blockDim.x + threadIdx.x;
  if (i >= n4) return;
  float4 v = ((const float4*)in)[i];
  short4 o;
  o.x = f2bf(v.x); o.y = f2bf(v.y); o.z = f2bf(v.z); o.w = f2bf(v.w);
  ((short4*)out)[i] = o;
}

// ---------------- shared 128x128 GEMM body: C = act(A @ W^T + bias) ----------------
// K = N = HH compile-time. 256 threads / 4 waves, each wave 64x64 of 4x4
// mfma_f32_16x16x32_bf16. global_load_lds width-16 staging (m97 structure).
__device__ __forceinline__ void gemm128_body(
    const short* __restrict__ A, const short* __restrict__ W,
    const float* __restrict__ bias, short* __restrict__ C,
    int m0, int n0, bool act)
{
  __shared__ __align__(16) short sA[128*32];
  __shared__ __align__(16) short sW[128*32];
  const int t    = threadIdx.x;
  const int lane = t & 63;
  const int wave = t >> 6;
  const int wr = (wave >> 1) * 64;
  const int wc = (wave & 1) * 64;
  const int srow = t >> 2;
  const int scol = (t & 3) * 8;
  const int fr = lane & 15;
  const int fk = (lane >> 4) * 8;

  f32x4 acc[4][4] = {};

  const short* Abase = A + (size_t)(m0 + srow) * HH + scol;
  const short* Wbase = W + (size_t)(n0 + srow) * HH + scol;
  char* lA0 = (char*)sA + t * 16;
  char* lA1 = (char*)sA + 4096 + t * 16;
  char* lW0 = (char*)sW + t * 16;
  char* lW1 = (char*)sW + 4096 + t * 16;

  for (int k0 = 0; k0 < HH; k0 += 32) {
    __syncthreads();
    gload_lds16(Abase + k0,                   lA0);
    gload_lds16(Abase + (size_t)64 * HH + k0, lA1);
    gload_lds16(Wbase + k0,                   lW0);
    gload_lds16(Wbase + (size_t)64 * HH + k0, lW1);
    __syncthreads();

    short8_t af[4], wf[4];
    #pragma unroll
    for (int i = 0; i < 4; i++)
      af[i] = *(const short8_t*)(sA + (wr + i * 16 + fr) * 32 + fk);
    #pragma unroll
    for (int j = 0; j < 4; j++)
      wf[j] = *(const short8_t*)(sW + (wc + j * 16 + fr) * 32 + fk);
    #pragma unroll
    for (int i = 0; i < 4; i++) {
      #pragma unroll
      for (int j = 0; j < 4; j++) {
        acc[i][j] = __builtin_amdgcn_mfma_f32_16x16x32_bf16(af[i], wf[j], acc[i][j], 0, 0, 0);
      }
    }
  }

  const int cr = (lane >> 4) * 4;
  const int cc = lane & 15;
  #pragma unroll
  for (int j = 0; j < 4; j++) {
    const int col = n0 + wc + j * 16 + cc;
    const float bv = bias[col];
    #pragma unroll
    for (int i = 0; i < 4; i++) {
      #pragma unroll
      for (int r = 0; r < 4; r++) {
        const int row = m0 + wr + i * 16 + cr + r;
        float v = acc[i][j][r] + bv;
        if (act) v = (v > 0.f) ? (v + 1.f) : __expf(v);
        C[(size_t)row * HH + col] = f2bf(v);
      }
    }
  }
}

// fused QKV: blockIdx.x = which*8 + ncol; consecutive x-blocks share the A tile (L2 reuse)
__global__ __launch_bounds__(256, 2) void qkv_gemm(
    const short* __restrict__ xb,
    const short* __restrict__ Wqb, const short* __restrict__ Wkb, const short* __restrict__ Wvb,
    const float* __restrict__ bq, const float* __restrict__ bk, const float* __restrict__ bv,
    short* __restrict__ Qo, short* __restrict__ Ko, short* __restrict__ Vo)
{
  const int which = blockIdx.x >> 3;
  const int n0 = (blockIdx.x & 7) * 128;
  const int m0 = blockIdx.y * 128;
  const short* W  = (which == 0) ? Wqb : (which == 1) ? Wkb : Wvb;
  const float* bs = (which == 0) ? bq  : (which == 1) ? bk  : bv;
  short* C        = (which == 0) ? Qo  : (which == 1) ? Ko  : Vo;
  gemm128_body(xb, W, bs, C, m0, n0, which < 2);
}

__global__ __launch_bounds__(256, 2) void dproj_gemm(
    const short* __restrict__ A, const short* __restrict__ W,
    const float* __restrict__ bias, short* __restrict__ C)
{
  gemm128_body(A, W, bias, C, blockIdx.y * 128, blockIdx.x * 128, false);
}

// ---------------- kv partials over S-splits ----------------
__global__ __launch_bounds__(256) void kv_part_kernel(
    const short* __restrict__ K_, const short* __restrict__ V_,
    float* __restrict__ kvpart, float* __restrict__ kspart)
{
  __shared__ __align__(16) float sK[32 * 64];
  __shared__ __align__(16) float sV[32 * 64];
  const int h = blockIdx.x, b = blockIdx.y, sp = blockIdx.z;
  const int t = threadIdx.x;
  const int m = t & 63;
  const int dg = (t >> 6) * 16;
  const int lrow = t >> 3;
  const int lcol = (t & 7) * 8;
  const int SC = SS / KVSPLIT;
  float acc[16] = {};
  float ks = 0.f;
  const size_t base = ((size_t)b * SS + (size_t)sp * SC) * HH + (size_t)h * HDD;
  const short* Kp = K_ + base + (size_t)lrow * HH + lcol;
  const short* Vp = V_ + base + (size_t)lrow * HH + lcol;

  for (int sc = 0; sc < SC; sc += 32) {
    short8_t k8 = *(const short8_t*)(Kp + (size_t)sc * HH);
    short8_t v8 = *(const short8_t*)(Vp + (size_t)sc * HH);
    __syncthreads();
    #pragma unroll
    for (int j = 0; j < 8; j++) {
      sK[lrow * 64 + lcol + j] = bf2f(k8[j]);
      sV[lrow * 64 + lcol + j] = bf2f(v8[j]);
    }
    __syncthreads();
    if (t < 64) {
      #pragma unroll
      for (int ss = 0; ss < 32; ss++) ks += sK[ss * 64 + t];
    }
    #pragma unroll 4
    for (int ss = 0; ss < 32; ss++) {
      const float vm = sV[ss * 64 + m];
      const float* kr = sK + ss * 64 + dg;
      #pragma unroll
      for (int j = 0; j < 16; j++) acc[j] += kr[j] * vm;
    }
  }

  const int bh = b * NHH + h;
  float* kvp = kvpart + (size_t)(bh * KVSPLIT + sp) * 4096 + m * 64 + dg;
  #pragma unroll
  for (int j = 0; j < 16; j += 4) {
    f32x4 o;
    o[0] = acc[j]; o[1] = acc[j+1]; o[2] = acc[j+2]; o[3] = acc[j+3];
    *(f32x4*)(kvp + j) = o;
  }
  if (t < 64) kspart[(bh * KVSPLIT + sp) * 64 + t] = ks;
}

// ---------------- reduce partials -> kv bf16 [bh][m][d], ksum fp32 ----------------
__global__ __launch_bounds__(256) void kv_reduce_kernel(
    const float* __restrict__ kvpart, const float* __restrict__ kspart,
    short* __restrict__ kvbf, float* __restrict__ ksum)
{
  const int bh = blockIdx.x;
  const int t = threadIdx.x;
  const float* src = kvpart + (size_t)bh * KVSPLIT * 4096;
  #pragma unroll
  for (int i = 0; i < 4; i++) {
    const int idx = t + i * 256;  // f32x4 index within 4096
    f32x4 s = {};
    #pragma unroll 4
    for (int p = 0; p < KVSPLIT; p++)
      s += ((const f32x4*)(src + (size_t)p * 4096))[idx];
    short4 o;
    o.x = f2bf(s[0]); o.y = f2bf(s[1]); o.z = f2bf(s[2]); o.w = f2bf(s[3]);
    ((short4*)(kvbf + (size_t)bh * 4096))[idx] = o;
  }
  if (t < 64) {
    float s = 0.f;
    #pragma unroll
    for (int p = 0; p < KVSPLIT; p++) s += kspart[(bh * KVSPLIT + p) * 64 + t];
    ksum[bh * 64 + t] = s + 1e-6f;
  }
}

// ---------------- ctx via MFMA: per (b,h), ctx = diag(z) . Q[4096x64] @ kv[64x64]^T ----------------
// block = 256 threads / 4 waves, 256 tokens. A-fragments straight from global
// (row-contiguous 16B). kv staged in LDS bf16 with stride-72 padding (bank-safe).
__global__ __launch_bounds__(256) void ctx_mfma(
    const short* __restrict__ Q, const short* __restrict__ kvbf,
    const float* __restrict__ ksum, short* __restrict__ ctx)
{
  __shared__ __align__(16) short sB[64 * 72];
  __shared__ float sks[64];
  __shared__ float sz[256];
  const int b = blockIdx.z, h = blockIdx.y;
  const int t = threadIdx.x;
  const int lane = t & 63, wave = t >> 6;
  const int s0 = blockIdx.x * 256;
  const int bh = b * NHH + h;

  { // stage kv -> LDS (padded)
    const short8_t* src = (const short8_t*)(kvbf + (size_t)bh * 4096);
    const int m = t >> 2, c = (t & 3) * 16;
    short8_t v0 = src[t * 2], v1 = src[t * 2 + 1];
    *(short8_t*)(sB + m * 72 + c)     = v0;
    *(short8_t*)(sB + m * 72 + c + 8) = v1;
  }
  if (t < 64) sks[t] = ksum[bh * 64 + t];
  __syncthreads();

  { // per-token normalizer z = 1/(q . ksum)
    const short* qp = Q + (size_t)(b * SS + s0 + t) * HH + h * HDD;
    float zden = 0.f;
    #pragma unroll
    for (int i = 0; i < 8; i++) {
      short8_t q8 = *(const short8_t*)(qp + i * 8);
      #pragma unroll
      for (int j = 0; j < 8; j++) zden += bf2f(q8[j]) * sks[i * 8 + j];
    }
    sz[t] = 1.f / zden;
  }
  __syncthreads();

  const int fr = lane & 15, fk = (lane >> 4) * 8;
  const int wrow = wave * 64;
  f32x4 acc[4][4] = {};
  const short* qbase = Q + (size_t)(b * SS + s0 + wrow + fr) * HH + h * HDD + fk;
  #pragma unroll
  for (int k0 = 0; k0 < 64; k0 += 32) {
    short8_t af[4], wf[4];
    #pragma unroll
    for (int i = 0; i < 4; i++)
      af[i] = *(const short8_t*)(qbase + (size_t)(i * 16) * HH + k0);
    #pragma unroll
    for (int j = 0; j < 4; j++)
      wf[j] = *(const short8_t*)(sB + (j * 16 + fr) * 72 + fk + k0);
    #pragma unroll
    for (int i = 0; i < 4; i++) {
      #pragma unroll
      for (int j = 0; j < 4; j++) {
        acc[i][j] = __builtin_amdgcn_mfma_f32_16x16x32_bf16(af[i], wf[j], acc[i][j], 0, 0, 0);
      }
    }
  }

  const int cr = (lane >> 4) * 4, cc = lane & 15;
  short* cp = ctx + ((size_t)(b * SS + s0)) * HH + h * HDD;
  #pragma unroll
  for (int j = 0; j < 4; j++) {
    const int col = j * 16 + cc;
    #pragma unroll
    for (int i = 0; i < 4; i++) {
      #pragma unroll
      for (int r = 0; r < 4; r++) {
        const int row = wrow + i * 16 + cr + r;
        cp[(size_t)row * HH + col] = f2bf(acc[i][j][r] * sz[row]);
      }
    }
  }
}

// ---------------- LayerNorm(P + x) * gamma + beta ----------------
__global__ __launch_bounds__(256) void ln_kernel(
    const short* __restrict__ P, const float* __restrict__ x,
    const float* __restrict__ gamma, const float* __restrict__ beta,
    float* __restrict__ out)
{
  const int row = blockIdx.x;
  const int t = threadIdx.x;
  const short* pr = P + (size_t)row * HH;
  const float* xr = x + (size_t)row * HH;
  short4 p4 = ((const short4*)pr)[t];
  float4 x4 = ((const float4*)xr)[t];
  float h0 = bf2f(p4.x) + x4.x;
  float h1 = bf2f(p4.y) + x4.y;
  float h2 = bf2f(p4.z) + x4.z;
  float h3 = bf2f(p4.w) + x4.w;
  float s1 = h0 + h1 + h2 + h3;
  float s2 = h0*h0 + h1*h1 + h2*h2 + h3*h3;
  #pragma unroll
  for (int o = 32; o > 0; o >>= 1) {
    s1 += __shfl_xor(s1, o);
    s2 += __shfl_xor(s2, o);
  }
  __shared__ float red[8];
  const int wv = t >> 6, ln = t & 63;
  if (ln == 0) { red[wv] = s1; red[4 + wv] = s2; }
  __syncthreads();
  const float S1 = red[0] + red[1] + red[2] + red[3];
  const float S2 = red[4] + red[5] + red[6] + red[7];
  const float mu  = S1 * (1.f / HH);
  const float var = S2 * (1.f / HH) - mu * mu;
  const float inv = rsqrtf(var + 1e-12f);
  float4 g4 = ((const float4*)gamma)[t];
  float4 b4 = ((const float4*)beta)[t];
  float4 o4;
  o4.x = (h0 - mu) * inv * g4.x + b4.x;
  o4.y = (h1 - mu) * inv * g4.y + b4.y;
  o4.z = (h2 - mu) * inv * g4.z + b4.z;
  o4.w = (h3 - mu) * inv * g4.w + b4.w;
  ((float4*)(out + (size_t)row * HH))[t] = o4;
}

extern "C" void kernel_launch(void* const* d_in, const int* in_sizes, int n_in,
                              void* d_out, int out_size, void* d_ws, size_t ws_size,
                              hipStream_t stream)
{
  const float* x     = (const float*)d_in[0];
  // d_in[1] = attention_mask: unused (all zeros; reference ignores it)
  const float* Wq    = (const float*)d_in[2];
  const float* bq    = (const float*)d_in[3];
  const float* Wk    = (const float*)d_in[4];
  const float* bk    = (const float*)d_in[5];
  const float* Wv    = (const float*)d_in[6];
  const float* bv    = (const float*)d_in[7];
  const float* Wd    = (const float*)d_in[8];
  const float* bd    = (const float*)d_in[9];
  const float* gamma = (const float*)d_in[10];
  const float* beta  = (const float*)d_in[11];
  float* out = (float*)d_out;

  char* ws = (char*)d_ws;
  const size_t MB64 = 67108864;
  short* xb  = (short*)(ws + 0 * MB64);
  short* Qb  = (short*)(ws + 1 * MB64);
  short* Kb  = (short*)(ws + 2 * MB64);
  short* Vb  = (short*)(ws + 3 * MB64);
  short* Cb  = (short*)(ws + 4 * MB64);
  short* Wqb = (short*)(ws + 5 * MB64 + 0 * 2097152);
  short* Wkb = (short*)(ws + 5 * MB64 + 1 * 2097152);
  short* Wvb = (short*)(ws + 5 * MB64 + 2 * 2097152);
  short* Wdb = (short*)(ws + 5 * MB64 + 3 * 2097152);
  short* kvbf= (short*)(ws + 5 * MB64 + 4 * 2097152);
  float* ksb = (float*)(ws + 5 * MB64 + 5 * 2097152);
  // kv partials overlay Cb region (not live until ctx_mfma)
  float* kvpart = (float*)(ws + 4 * MB64);
  float* kspart = kvpart + (size_t)128 * KVSPLIT * 4096;
  short* Pb  = Qb;  // Q dead after ctx_mfma

  cvt_bf16<<<(MM * HH / 4) / 256, 256, 0, stream>>>(x,  xb,  MM * HH / 4);
  cvt_bf16<<<(HH * HH / 4) / 256, 256, 0, stream>>>(Wq, Wqb, HH * HH / 4);
  cvt_bf16<<<(HH * HH / 4) / 256, 256, 0, stream>>>(Wk, Wkb, HH * HH / 4);
  cvt_bf16<<<(HH * HH / 4) / 256, 256, 0, stream>>>(Wv, Wvb, HH * HH / 4);
  cvt_bf16<<<(HH * HH / 4) / 256, 256, 0, stream>>>(Wd, Wdb, HH * HH / 4);

  qkv_gemm<<<dim3(24, MM / 128), 256, 0, stream>>>(xb, Wqb, Wkb, Wvb, bq, bk, bv, Qb, Kb, Vb);

  kv_part_kernel<<<dim3(NHH, BB, KVSPLIT), 256, 0, stream>>>(Kb, Vb, kvpart, kspart);
  kv_reduce_kernel<<<BB * NHH, 256, 0, stream>>>(kvpart, kspart, kvbf, ksb);
  ctx_mfma<<<dim3(SS / 256, NHH, BB), 256, 0, stream>>>(Qb, kvbf, ksb, Cb);

  dproj_gemm<<<dim3(HH / 128, MM / 128), 256, 0, stream>>>(Cb, Wdb, bd, Pb);
  ln_kernel<<<MM, 256, 0, stream>>>(Pb, x, gamma, beta, out);
}